// Round 15
// baseline (324.130 us; speedup 1.0000x reference)
//
#include <hip/hip_runtime.h>
#include <cstddef>

#define NN 25600
#define BB 64
#define NPG 400
#define KK 16
#define LL 4

typedef _Float16 half_t;
typedef _Float16 h8 __attribute__((ext_vector_type(8)));
typedef _Float16 h4 __attribute__((ext_vector_type(4)));
typedef _Float16 h2 __attribute__((ext_vector_type(2)));
typedef float f32x4 __attribute__((ext_vector_type(4)));

// ---------------- weight prep: split-fp16 weights in MFMA FRAGMENT order ----
__global__ __launch_bounds__(256) void prep_k(const float* __restrict__ preW,
                                              const float* __restrict__ preb,
                                              const float* __restrict__ postW,
                                              half_t* __restrict__ WpreH,
                                              half_t* __restrict__ WpreL,
                                              float* __restrict__ bpre,
                                              half_t* __restrict__ WpostH,
                                              half_t* __restrict__ WpostL) {
  int idx = blockIdx.x * 256 + threadIdx.x;
  const int n1 = LL * 256 * 128;          // 131072
  const int n2 = n1 + LL * 256;           // +1024
  const int n3 = n2 + LL * 128 * 512;     // +262144
  if (idx < n1) {
    int l = idx / 32768;
    int q = idx % 32768;
    int j = q & 7, lane = (q >> 3) & 63, kc = (q >> 9) & 3, c16 = q >> 11;  // c16 0..15
    int col = c16 * 16 + (lane & 15);
    int k = kc * 32 + (lane >> 4) * 8 + j;
    float v = (col < 128) ? preW[(size_t)l * 32768 + (size_t)col * 256 + k]
                          : preW[(size_t)l * 32768 + (size_t)(col - 128) * 256 + 128 + k];
    half_t hi = (half_t)v;
    WpreH[idx] = hi;
    WpreL[idx] = (half_t)(v - (float)hi);
  } else if (idx < n2) {
    int r = idx - n1;
    int l = r / 256, o = r % 256;
    bpre[r] = (o < 128) ? 0.f : preb[l * 128 + (o - 128)];
  } else if (idx < n3) {
    int r = idx - n2;
    int l = r / 65536;
    int q = r % 65536;
    int j = q & 7, lane = (q >> 3) & 63, kc = (q >> 9) & 15, c16 = q >> 13;  // c16 0..7
    int col = c16 * 16 + (lane & 15);
    int k = kc * 32 + (lane >> 4) * 8 + j;
    int jblk = k >> 7, kk = k & 127;
    const float* base = postW + (size_t)l * 128 * 640 + (size_t)col * 640;
    float v;
    if (jblk == 0)      v = base[kk];
    else if (jblk == 1) v = base[128 + kk] * (1.f / 16.f) + base[256 + kk];
    else if (jblk == 2) v = base[384 + kk];
    else                v = base[512 + kk];
    half_t hi = (half_t)v;
    WpostH[r] = hi;
    WpostL[r] = (half_t)(v - (float)hi);
  }
}

// ---------------- embed gather: Hh/Hl (N x 128 split f16) ------------------
__global__ __launch_bounds__(256) void embed_k(const int* __restrict__ nf,
                                               const float* __restrict__ emb,
                                               half_t* __restrict__ Hh,
                                               half_t* __restrict__ Hl) {
  int idx = blockIdx.x * 256 + threadIdx.x;  // over N*32 float4s
  int n = idx >> 5;
  int d4 = idx & 31;
  int a = nf[n];
  float4 v = *(const float4*)(emb + (size_t)a * 128 + d4 * 4);
  h4 hi, lo;
  const float* vp = &v.x;
#pragma unroll
  for (int j = 0; j < 4; ++j) {
    half_t h = (half_t)vp[j];
    hi[j] = h;
    lo[j] = (half_t)(vp[j] - (float)h);
  }
  *(h4*)(Hh + (size_t)n * 128 + d4 * 4) = hi;
  *(h4*)(Hl + (size_t)n * 128 + d4 * 4) = lo;
}

// ---------------- K1: pre-GEMM, grid (400,2): y=0 -> preA, y=1 -> b --------
__global__ __launch_bounds__(256) void pre_gemm_k(const half_t* __restrict__ Ah_g,
                                                  const half_t* __restrict__ Al_g,
                                                  const half_t* __restrict__ Wh_g,
                                                  const half_t* __restrict__ Wl_g,
                                                  const float* __restrict__ bpre128,
                                                  float* __restrict__ preA,
                                                  float* __restrict__ bF) {
  __shared__ half_t Ahs[64][132];
  __shared__ half_t Als[64][132];
  const int tid = threadIdx.x;
  const int bid = blockIdx.x;                      // 0..399
  const int y = blockIdx.y;                        // 0: A-side, 1: B-side
  const int swz = (bid & 7) * 50 + (bid >> 3);     // XCD-contiguous rows
  const int r0 = swz * 64;
  const int wid = tid >> 6, lane = tid & 63;
  const int wm = wid >> 1, wn = wid & 1;
  const int lr = lane & 15, lk = (lane >> 4) * 8;
  f32x4 acc[2][4] = {};

  // stage full A tile (64 x 128, hi+lo)
  {
    const int row = tid >> 2;
#pragma unroll
    for (int s = 0; s < 4; ++s) {
      const int koff = (tid & 3) * 8 + s * 32;
      const size_t g = (size_t)(r0 + row) * 128 + koff;
      *(h8*)&Ahs[row][koff] = *(const h8*)(Ah_g + g);
      *(h8*)&Als[row][koff] = *(const h8*)(Al_g + g);
    }
  }
  __syncthreads();

#pragma unroll
  for (int kc = 0; kc < 4; ++kc) {
    h8 af[2][2];
#pragma unroll
    for (int mi = 0; mi < 2; ++mi) {
      const int r = wm * 32 + mi * 16 + lr;
      af[mi][0] = *(const h8*)&Ahs[r][kc * 32 + lk];
      af[mi][1] = *(const h8*)&Als[r][kc * 32 + lk];
    }
#pragma unroll
    for (int nj = 0; nj < 4; ++nj) {
      const size_t fi = ((size_t)((y * 8 + wn * 4 + nj) * 4 + kc) * 64 + lane) * 8;
      const h8 b0v = *(const h8*)(Wh_g + fi);
      const h8 b1v = *(const h8*)(Wl_g + fi);
#pragma unroll
      for (int mi = 0; mi < 2; ++mi) {
        acc[mi][nj] = __builtin_amdgcn_mfma_f32_16x16x32_f16(af[mi][0], b0v, acc[mi][nj], 0, 0, 0);
        acc[mi][nj] = __builtin_amdgcn_mfma_f32_16x16x32_f16(af[mi][0], b1v, acc[mi][nj], 0, 0, 0);
        acc[mi][nj] = __builtin_amdgcn_mfma_f32_16x16x32_f16(af[mi][1], b0v, acc[mi][nj], 0, 0, 0);
      }
    }
  }
  // epilogue: C/D layout col=lane&15, row=(lane>>4)*4+q
  float* outp = (y == 0) ? preA : bF;
#pragma unroll
  for (int mi = 0; mi < 2; ++mi) {
    const int rowb = r0 + wm * 32 + mi * 16 + (lane >> 4) * 4;
#pragma unroll
    for (int nj = 0; nj < 4; ++nj) {
      const int col = wn * 64 + nj * 16 + lr;
      const float bv = (y == 0) ? 0.f : bpre128[col];
#pragma unroll
      for (int q = 0; q < 4; ++q) {
        outp[(size_t)(rowb + q) * 128 + col] = acc[mi][nj][q] + bv;
      }
    }
  }
}

// ---------------- K2: edge aggregation (wave = node, pure TLP) -------------
// Writes the full split-f16 post-GEMM A-matrix row: AhG/AlG[N][512] =
// [h (copied) | s | mx | dir]. Register-batched gathers, shuffle merge.
__global__ __launch_bounds__(256) void agg_k(const float* __restrict__ preA,
                                             const float* __restrict__ bF,
                                             const int* __restrict__ src,
                                             const float* __restrict__ eig,
                                             const half_t* __restrict__ Hh,
                                             const half_t* __restrict__ Hl,
                                             half_t* __restrict__ AhG,
                                             half_t* __restrict__ AlG) {
  const int bid = blockIdx.x;                       // 0..6399
  const int swz = (bid & 7) * 800 + (bid >> 3);     // XCD-contiguous
  const int wid = threadIdx.x >> 6, lane = threadIdx.x & 63;
  const int n = swz * 4 + wid;
  const int gsel = lane >> 5;                       // 0: even rows, 1: odd rows
  const int m4 = (lane & 31) * 4;                   // this lane's 4 columns

  int sv[KK];
  float wv[KK];
  {
    const int4* sp4 = (const int4*)(src + (size_t)n * KK);
    const float4* ep4 = (const float4*)(eig + (size_t)n * KK * 2);
#pragma unroll
    for (int t = 0; t < 4; ++t) {
      const int4 s4 = sp4[t];
      sv[4 * t + 0] = s4.x; sv[4 * t + 1] = s4.y;
      sv[4 * t + 2] = s4.z; sv[4 * t + 3] = s4.w;
    }
#pragma unroll
    for (int t = 0; t < 8; ++t) {
      const float4 e4 = ep4[t];
      wv[2 * t + 0] = e4.y; wv[2 * t + 1] = e4.w;
    }
  }
  // 8 independent named-register gathers (this lane's half of 16 rows)
  float4 g0 = *(const float4*)(preA + (size_t)sv[0 + gsel] * 128 + m4);
  float4 g1 = *(const float4*)(preA + (size_t)sv[2 + gsel] * 128 + m4);
  float4 g2 = *(const float4*)(preA + (size_t)sv[4 + gsel] * 128 + m4);
  float4 g3 = *(const float4*)(preA + (size_t)sv[6 + gsel] * 128 + m4);
  float4 g4 = *(const float4*)(preA + (size_t)sv[8 + gsel] * 128 + m4);
  float4 g5 = *(const float4*)(preA + (size_t)sv[10 + gsel] * 128 + m4);
  float4 g6 = *(const float4*)(preA + (size_t)sv[12 + gsel] * 128 + m4);
  float4 g7 = *(const float4*)(preA + (size_t)sv[14 + gsel] * 128 + m4);
  // weights (VALU overlaps loads)
  float denom = 0.f;
#pragma unroll
  for (int e = 0; e < KK; ++e) denom += fabsf(wv[e]);
  denom += 1e-8f;
  const float inv = 1.f / denom;
  float sum_ew = 0.f;
#pragma unroll
  for (int e = 0; e < KK; ++e) {
    wv[e] *= inv;
    sum_ew += wv[e];
  }
  float sx = 0.f, sy = 0.f, sz = 0.f, sw_ = 0.f;
  float wx = 0.f, wy = 0.f, wz = 0.f, ww = 0.f;
  float mx = -3.402823466e+38f, my = mx, mz = mx, mw = mx;
#define ACC(G, J)                                                   \
  {                                                                 \
    const float we = wv[2 * (J) + gsel];                            \
    sx += G.x; sy += G.y; sz += G.z; sw_ += G.w;                    \
    wx = fmaf(we, G.x, wx); wy = fmaf(we, G.y, wy);                 \
    wz = fmaf(we, G.z, wz); ww = fmaf(we, G.w, ww);                 \
    mx = fmaxf(mx, G.x); my = fmaxf(my, G.y);                       \
    mz = fmaxf(mz, G.z); mw = fmaxf(mw, G.w);                       \
  }
  ACC(g0, 0) ACC(g1, 1) ACC(g2, 2) ACC(g3, 3)
  ACC(g4, 4) ACC(g5, 5) ACC(g6, 6) ACC(g7, 7)
#undef ACC
  // merge even/odd halves across lane^32
  sx += __shfl_xor(sx, 32); sy += __shfl_xor(sy, 32);
  sz += __shfl_xor(sz, 32); sw_ += __shfl_xor(sw_, 32);
  wx += __shfl_xor(wx, 32); wy += __shfl_xor(wy, 32);
  wz += __shfl_xor(wz, 32); ww += __shfl_xor(ww, 32);
  mx = fmaxf(mx, __shfl_xor(mx, 32)); my = fmaxf(my, __shfl_xor(my, 32));
  mz = fmaxf(mz, __shfl_xor(mz, 32)); mw = fmaxf(mw, __shfl_xor(mw, 32));

  if (lane < 32) {
    const float4 b4 = *(const float4*)(bF + (size_t)n * 128 + m4);
    const h4 hh4 = *(const h4*)(Hh + (size_t)n * 128 + m4);
    const h4 hl4 = *(const h4*)(Hl + (size_t)n * 128 + m4);
    const float h0 = (float)hh4[0] + (float)hl4[0];
    const float h1 = (float)hh4[1] + (float)hl4[1];
    const float h2v = (float)hh4[2] + (float)hl4[2];
    const float h3 = (float)hh4[3] + (float)hl4[3];
    half_t* ah = AhG + (size_t)n * 512;
    half_t* al = AlG + (size_t)n * 512;
    // h-part: exact copy
    *(h4*)(ah + m4) = hh4;
    *(h4*)(al + m4) = hl4;
    auto wr4 = [&](int kcol, float v0, float v1, float v2, float v3) {
      h4 hi, lo;
      hi[0] = (half_t)v0; lo[0] = (half_t)(v0 - (float)hi[0]);
      hi[1] = (half_t)v1; lo[1] = (half_t)(v1 - (float)hi[1]);
      hi[2] = (half_t)v2; lo[2] = (half_t)(v2 - (float)hi[2]);
      hi[3] = (half_t)v3; lo[3] = (half_t)(v3 - (float)hi[3]);
      *(h4*)(ah + kcol) = hi;
      *(h4*)(al + kcol) = lo;
    };
    wr4(128 + m4, sx + 16.f * b4.x, sy + 16.f * b4.y, sz + 16.f * b4.z, sw_ + 16.f * b4.w);
    wr4(256 + m4, mx + b4.x, my + b4.y, mz + b4.z, mw + b4.w);
    wr4(384 + m4,
        fabsf(wx + sum_ew * (b4.x - h0)), fabsf(wy + sum_ew * (b4.y - h1)),
        fabsf(wz + sum_ew * (b4.z - h2v)), fabsf(ww + sum_ew * (b4.w - h3)));
  }
}

// ---------------- K3: post-GEMM K=512 (16-row tiles, grid 1600) ------------
// Stages AhG/AlG rows to LDS (coalesced), computes 16x32 wave tiles, residual
// read from the staged h-part, writes new Hh/Hl.
__global__ __launch_bounds__(256) void post_gemm_k(const half_t* __restrict__ AhG,
                                                   const half_t* __restrict__ AlG,
                                                   const half_t* __restrict__ Wh,
                                                   const half_t* __restrict__ Wl,
                                                   const float* __restrict__ bias,
                                                   const float* __restrict__ snorm,
                                                   half_t* __restrict__ Hh,
                                                   half_t* __restrict__ Hl) {
  __shared__ half_t AhS[16][520];
  __shared__ half_t AlS[16][520];
  const int tid = threadIdx.x;
  const int bid = blockIdx.x;                       // 0..1599
  const int swz = (bid & 7) * 200 + (bid >> 3);     // XCD-contiguous rows
  const int r0 = swz * 16;
  const int wid = tid >> 6, lane = tid & 63;
  const int wn = wid;                               // cols wn*32
  const int lr = lane & 15, lk = (lane >> 4) * 8;

  // stage 16 rows x 512 halves x 2 planes (coalesced h8 loads)
#pragma unroll
  for (int it = 0; it < 4; ++it) {
    const int id = it * 256 + tid;                  // 0..1023
    const int r = id >> 6;
    const int c = (id & 63) * 8;
    *(h8*)&AhS[r][c] = *(const h8*)(AhG + (size_t)(r0 + r) * 512 + c);
    *(h8*)&AlS[r][c] = *(const h8*)(AlG + (size_t)(r0 + r) * 512 + c);
  }
  __syncthreads();

  f32x4 acc[2] = {};
#pragma unroll
  for (int kc = 0; kc < 16; ++kc) {
    const h8 a0 = *(const h8*)&AhS[lr][kc * 32 + lk];
    const h8 a1 = *(const h8*)&AlS[lr][kc * 32 + lk];
#pragma unroll
    for (int nj = 0; nj < 2; ++nj) {
      const size_t fi = ((size_t)((wn * 2 + nj) * 16 + kc) * 64 + lane) * 8;
      const h8 b0v = *(const h8*)(Wh + fi);
      const h8 b1v = *(const h8*)(Wl + fi);
      acc[nj] = __builtin_amdgcn_mfma_f32_16x16x32_f16(a0, b0v, acc[nj], 0, 0, 0);
      acc[nj] = __builtin_amdgcn_mfma_f32_16x16x32_f16(a0, b1v, acc[nj], 0, 0, 0);
      acc[nj] = __builtin_amdgcn_mfma_f32_16x16x32_f16(a1, b0v, acc[nj], 0, 0, 0);
    }
  }

  // epilogue: hn = h_old + relu((acc+bias)*snorm); h_old from staged h-part
  const int rowb = (lane >> 4) * 4;
#pragma unroll
  for (int nj = 0; nj < 2; ++nj) {
    const int col = wn * 32 + nj * 16 + lr;
    const float bv = bias[col];
#pragma unroll
    for (int q = 0; q < 4; ++q) {
      const int r = rowb + q;
      const int grow = r0 + r;
      float a = acc[nj][q] + bv;
      a *= snorm[grow];
      a = fmaxf(a, 0.f);
      const float hold = (float)AhS[r][col] + (float)AlS[r][col];
      const float hn = hold + a;
      const half_t hi = (half_t)hn;
      const size_t off = (size_t)grow * 128 + col;
      Hh[off] = hi;
      Hl[off] = (half_t)(hn - (float)hi);
    }
  }
}

// ---------------- fused graph-mean + readout MLP (64 blocks) ---------------
__global__ __launch_bounds__(256) void reduce_mlp_k(const half_t* __restrict__ Hh,
                                                    const half_t* __restrict__ Hl,
                                                    const float* __restrict__ W0, const float* __restrict__ b0,
                                                    const float* __restrict__ W1, const float* __restrict__ b1,
                                                    const float* __restrict__ W2, const float* __restrict__ b2,
                                                    float* __restrict__ out) {
  __shared__ float hgs[128];
  __shared__ float red[128];
  __shared__ float y0s[64];
  __shared__ float y1s[32];
  __shared__ float wb[64 * 130];
  const int g = blockIdx.x;
  const int t = threadIdx.x;
  {
    const int d = t & 127, hf = t >> 7;
    const size_t base = ((size_t)g * NPG + (size_t)hf * 200) * 128 + d;
    float acc = 0.f;
    for (int i = 0; i < 200; ++i) {
      const size_t off = base + (size_t)i * 128;
      acc += (float)Hh[off] + (float)Hl[off];
    }
    if (hf) red[d] = acc;
    __syncthreads();
    if (!hf) hgs[d] = (acc + red[d]) * (1.f / (float)NPG);
  }
  __syncthreads();
  for (int idx = t; idx < 64 * 128; idx += 256) {
    wb[(idx >> 7) * 130 + (idx & 127)] = W0[idx];
  }
  __syncthreads();
  if (t < 64) {
    float a = b0[t];
    const float* w = &wb[t * 130];
    for (int k = 0; k < 128; ++k) a = fmaf(hgs[k], w[k], a);
    y0s[t] = fmaxf(a, 0.f);
  }
  __syncthreads();
  for (int idx = t; idx < 32 * 64; idx += 256) {
    wb[(idx >> 6) * 66 + (idx & 63)] = W1[idx];
  }
  __syncthreads();
  if (t < 32) {
    float a = b1[t];
    const float* w = &wb[t * 66];
    for (int k = 0; k < 64; ++k) a = fmaf(y0s[k], w[k], a);
    y1s[t] = fmaxf(a, 0.f);
  }
  __syncthreads();
  for (int idx = t; idx < 128 * 32; idx += 256) {
    wb[(idx >> 5) * 34 + (idx & 31)] = W2[idx];
  }
  __syncthreads();
  if (t < 128) {
    float a = b2[t];
    const float* w = &wb[t * 34];
    for (int k = 0; k < 32; ++k) a = fmaf(y1s[k], w[k], a);
    out[(size_t)g * 128 + t] = a;
  }
}

extern "C" void kernel_launch(void* const* d_in, const int* in_sizes, int n_in,
                              void* d_out, int out_size, void* d_ws, size_t ws_size,
                              hipStream_t stream) {
  const int* node_feat = (const int*)d_in[0];
  const int* src = (const int*)d_in[1];
  // d_in[2] = dst (repeat(arange(N),16)), unused
  const float* eig = (const float*)d_in[3];
  const float* snorm = (const float*)d_in[4];
  // d_in[5] = graph_ids, unused
  const float* emb = (const float*)d_in[6];
  const float* preW = (const float*)d_in[7];
  const float* preb = (const float*)d_in[8];
  const float* postW = (const float*)d_in[9];
  const float* postb = (const float*)d_in[10];
  const float* rW0 = (const float*)d_in[11];
  const float* rb0 = (const float*)d_in[12];
  const float* rW1 = (const float*)d_in[13];
  const float* rb1 = (const float*)d_in[14];
  const float* rW2 = (const float*)d_in[15];
  const float* rb2 = (const float*)d_in[16];
  float* out = (float*)d_out;

  half_t* Hh = (half_t*)d_ws;                        // N*128
  half_t* Hl = Hh + (size_t)NN * 128;                // N*128
  float* preA = (float*)(Hl + (size_t)NN * 128);     // N*128 f32
  float* bF = preA + (size_t)NN * 128;               // N*128 f32
  half_t* AhG = (half_t*)(bF + (size_t)NN * 128);    // N*512
  half_t* AlG = AhG + (size_t)NN * 512;              // N*512
  half_t* WpreH = AlG + (size_t)NN * 512;            // L*32768 frag-major
  half_t* WpreL = WpreH + (size_t)LL * 32768;
  half_t* WpostH = WpreL + (size_t)LL * 32768;       // L*65536 frag-major
  half_t* WpostL = WpostH + (size_t)LL * 65536;
  float* bpre = (float*)(WpostL + (size_t)LL * 65536); // L*256

  prep_k<<<1540, 256, 0, stream>>>(preW, preb, postW, WpreH, WpreL, bpre, WpostH, WpostL);
  embed_k<<<(NN * 32) / 256, 256, 0, stream>>>(node_feat, emb, Hh, Hl);

  for (int l = 0; l < LL; ++l) {
    pre_gemm_k<<<dim3(NN / 64, 2), 256, 0, stream>>>(
        Hh, Hl, WpreH + (size_t)l * 32768, WpreL + (size_t)l * 32768,
        bpre + (size_t)l * 256 + 128, preA, bF);
    agg_k<<<NN / 4, 256, 0, stream>>>(preA, bF, src, eig, Hh, Hl, AhG, AlG);
    post_gemm_k<<<NN / 16, 256, 0, stream>>>(
        AhG, AlG, WpostH + (size_t)l * 65536, WpostL + (size_t)l * 65536,
        postb + (size_t)l * 128, snorm, Hh, Hl);
  }

  reduce_mlp_k<<<BB, 256, 0, stream>>>(Hh, Hl, rW0, rb0, rW1, rb1, rW2, rb2, out);
}

// Round 16
// 262.445 us; speedup vs baseline: 1.2350x; 1.2350x over previous
//
#include <hip/hip_runtime.h>
#include <cstddef>

#define NN 25600
#define BB 64
#define NPG 400
#define KK 16
#define LL 4

typedef _Float16 half_t;
typedef _Float16 h8 __attribute__((ext_vector_type(8)));
typedef _Float16 h4 __attribute__((ext_vector_type(4)));
typedef _Float16 h2 __attribute__((ext_vector_type(2)));
typedef float f32x4 __attribute__((ext_vector_type(4)));

#define GCAST(p) ((const __attribute__((address_space(1))) void*)(p))
#define SCAST(p) ((__attribute__((address_space(3))) void*)(p))

// ---------------- weight prep: split-fp16 weights in MFMA FRAGMENT order ----
__global__ __launch_bounds__(256) void prep_k(const float* __restrict__ preW,
                                              const float* __restrict__ preb,
                                              const float* __restrict__ postW,
                                              half_t* __restrict__ WpreH,
                                              half_t* __restrict__ WpreL,
                                              float* __restrict__ bpre,
                                              half_t* __restrict__ WpostH,
                                              half_t* __restrict__ WpostL) {
  int idx = blockIdx.x * 256 + threadIdx.x;
  const int n1 = LL * 256 * 128;          // 131072
  const int n2 = n1 + LL * 256;           // +1024
  const int n3 = n2 + LL * 128 * 512;     // +262144
  if (idx < n1) {
    int l = idx / 32768;
    int q = idx % 32768;
    int j = q & 7, lane = (q >> 3) & 63, kc = (q >> 9) & 3, c16 = q >> 11;  // c16 0..15
    int col = c16 * 16 + (lane & 15);
    int k = kc * 32 + (lane >> 4) * 8 + j;
    float v = (col < 128) ? preW[(size_t)l * 32768 + (size_t)col * 256 + k]
                          : preW[(size_t)l * 32768 + (size_t)(col - 128) * 256 + 128 + k];
    half_t hi = (half_t)v;
    WpreH[idx] = hi;
    WpreL[idx] = (half_t)(v - (float)hi);
  } else if (idx < n2) {
    int r = idx - n1;
    int l = r / 256, o = r % 256;
    bpre[r] = (o < 128) ? 0.f : preb[l * 128 + (o - 128)];
  } else if (idx < n3) {
    int r = idx - n2;
    int l = r / 65536;
    int q = r % 65536;
    int j = q & 7, lane = (q >> 3) & 63, kc = (q >> 9) & 15, c16 = q >> 13;  // c16 0..7
    int col = c16 * 16 + (lane & 15);
    int k = kc * 32 + (lane >> 4) * 8 + j;
    int jblk = k >> 7, kk = k & 127;
    const float* base = postW + (size_t)l * 128 * 640 + (size_t)col * 640;
    float v;
    if (jblk == 0)      v = base[kk];
    else if (jblk == 1) v = base[128 + kk] * (1.f / 16.f) + base[256 + kk];
    else if (jblk == 2) v = base[384 + kk];
    else                v = base[512 + kk];
    half_t hi = (half_t)v;
    WpostH[r] = hi;
    WpostL[r] = (half_t)(v - (float)hi);
  }
}

// ---------------- embed gather: Hh/Hl (N x 128 split f16) ------------------
__global__ __launch_bounds__(256) void embed_k(const int* __restrict__ nf,
                                               const float* __restrict__ emb,
                                               half_t* __restrict__ Hh,
                                               half_t* __restrict__ Hl) {
  int idx = blockIdx.x * 256 + threadIdx.x;  // over N*32 float4s
  int n = idx >> 5;
  int d4 = idx & 31;
  int a = nf[n];
  float4 v = *(const float4*)(emb + (size_t)a * 128 + d4 * 4);
  h4 hi, lo;
  const float* vp = &v.x;
#pragma unroll
  for (int j = 0; j < 4; ++j) {
    half_t h = (half_t)vp[j];
    hi[j] = h;
    lo[j] = (half_t)(vp[j] - (float)h);
  }
  *(h4*)(Hh + (size_t)n * 128 + d4 * 4) = hi;
  *(h4*)(Hl + (size_t)n * 128 + d4 * 4) = lo;
}

// ---------------- pre-GEMM (A-side only): preAh/preAl = split-f16 ----------
__global__ __launch_bounds__(256) void pre_gemm_k(const half_t* __restrict__ Ah_g,
                                                  const half_t* __restrict__ Al_g,
                                                  const half_t* __restrict__ Wh_g,
                                                  const half_t* __restrict__ Wl_g,
                                                  half_t* __restrict__ preAh,
                                                  half_t* __restrict__ preAl) {
  __shared__ half_t Ahs[64][132];
  __shared__ half_t Als[64][132];
  const int tid = threadIdx.x;
  const int bid = blockIdx.x;                      // 0..399
  const int swz = (bid & 7) * 50 + (bid >> 3);     // XCD-contiguous rows
  const int r0 = swz * 64;
  const int wid = tid >> 6, lane = tid & 63;
  const int wm = wid >> 1, wn = wid & 1;
  const int lr = lane & 15, lk = (lane >> 4) * 8;
  f32x4 acc[2][4] = {};

  // stage full A tile (64 x 128, hi+lo)
  {
    const int row = tid >> 2;
#pragma unroll
    for (int s = 0; s < 4; ++s) {
      const int koff = (tid & 3) * 8 + s * 32;
      const size_t g = (size_t)(r0 + row) * 128 + koff;
      *(h8*)&Ahs[row][koff] = *(const h8*)(Ah_g + g);
      *(h8*)&Als[row][koff] = *(const h8*)(Al_g + g);
    }
  }
  __syncthreads();

#pragma unroll
  for (int kc = 0; kc < 4; ++kc) {
    h8 af[2][2];
#pragma unroll
    for (int mi = 0; mi < 2; ++mi) {
      const int r = wm * 32 + mi * 16 + lr;
      af[mi][0] = *(const h8*)&Ahs[r][kc * 32 + lk];
      af[mi][1] = *(const h8*)&Als[r][kc * 32 + lk];
    }
#pragma unroll
    for (int nj = 0; nj < 4; ++nj) {
      const size_t fi = ((size_t)((wn * 4 + nj) * 4 + kc) * 64 + lane) * 8;
      const h8 b0v = *(const h8*)(Wh_g + fi);
      const h8 b1v = *(const h8*)(Wl_g + fi);
#pragma unroll
      for (int mi = 0; mi < 2; ++mi) {
        acc[mi][nj] = __builtin_amdgcn_mfma_f32_16x16x32_f16(af[mi][0], b0v, acc[mi][nj], 0, 0, 0);
        acc[mi][nj] = __builtin_amdgcn_mfma_f32_16x16x32_f16(af[mi][0], b1v, acc[mi][nj], 0, 0, 0);
        acc[mi][nj] = __builtin_amdgcn_mfma_f32_16x16x32_f16(af[mi][1], b0v, acc[mi][nj], 0, 0, 0);
      }
    }
  }
  // epilogue: C/D layout col=lane&15, row=(lane>>4)*4+q; split-f16 write
#pragma unroll
  for (int mi = 0; mi < 2; ++mi) {
    const int rowb = r0 + wm * 32 + mi * 16 + (lane >> 4) * 4;
#pragma unroll
    for (int nj = 0; nj < 4; ++nj) {
      const int col = wn * 64 + nj * 16 + lr;
#pragma unroll
      for (int q = 0; q < 4; ++q) {
        const float v = acc[mi][nj][q];
        const half_t hi = (half_t)v;
        const size_t off = (size_t)(rowb + q) * 128 + col;
        preAh[off] = hi;
        preAl[off] = (half_t)(v - (float)hi);
      }
    }
  }
}

// ---------------- fused B-side pre-GEMM + edge-agg + post-GEMM -------------
// block = 16 nodes, 4 waves. Step B gathers from SPLIT-F16 preA (L2-resident:
// 0.8 MB per XCD slice) via global_load_lds; per chunk of 8 rows: 2 DMA (hi)
// + 2 DMA (lo), each covering 4 rows of 256B. lgkmcnt(0) guards buffer reuse.
__global__ __launch_bounds__(256, 2) void agg_post_k(const half_t* __restrict__ preAh, // N x 128
                                                     const half_t* __restrict__ preAl,
                                                     const int* __restrict__ src,
                                                     const float* __restrict__ eig,   // E x 2
                                                     const half_t* __restrict__ WpHg, // pre frag-major
                                                     const half_t* __restrict__ WpLg,
                                                     const float* __restrict__ bpre128, // B-side bias
                                                     half_t* __restrict__ Hh,         // N x 128 (in/out)
                                                     half_t* __restrict__ Hl,
                                                     const half_t* __restrict__ Wh,   // post frag-major
                                                     const half_t* __restrict__ Wl,
                                                     const float* __restrict__ bias,  // 128
                                                     const float* __restrict__ snorm) {
  __shared__ half_t Ah[16][392];
  __shared__ half_t Al[16][392];
  __shared__ float bsh[16][132];
  __shared__ half_t stageH[4][8][128];             // per-wave gather staging (hi)
  __shared__ half_t stageL[4][8][128];             // (lo)
  const int tid = threadIdx.x;
  const int bid = blockIdx.x;                       // 0..1599
  const int swz = (bid & 7) * 200 + (bid >> 3);     // XCD-contiguous nodes
  const int r0 = swz * 16;
  const int wid = tid >> 6, lane = tid & 63;
  const int wn = wid;                               // 4 waves split 128 cols
  const int lr = lane & 15, lk = (lane >> 4) * 8;
  const int d0 = 2 * lane;
  const int grow4 = lane >> 4;                      // row within a 4-row DMA
  const int gcol8 = (lane & 15) * 8;                // half-offset (16B granule)

  // prefetch h fragments for this block's 16 rows
  const int frow = r0 + lr;
  h8 afh[4][2];
#pragma unroll
  for (int hc = 0; hc < 4; ++hc) {
    afh[hc][0] = *(const h8*)(Hh + (size_t)frow * 128 + hc * 32 + lk);
    afh[hc][1] = *(const h8*)(Hl + (size_t)frow * 128 + hc * 32 + lk);
  }

  // ---- step A: b = Hcat @ WpB^T + bias(B-side) -> bsh[16][128] ----
  {
    f32x4 bacc[2] = {};
#pragma unroll
    for (int kc = 0; kc < 4; ++kc) {
#pragma unroll
      for (int nj = 0; nj < 2; ++nj) {
        const size_t fi = ((size_t)((8 + wn * 2 + nj) * 4 + kc) * 64 + lane) * 8;
        const h8 b0v = *(const h8*)(WpHg + fi);
        const h8 b1v = *(const h8*)(WpLg + fi);
        bacc[nj] = __builtin_amdgcn_mfma_f32_16x16x32_f16(afh[kc][0], b0v, bacc[nj], 0, 0, 0);
        bacc[nj] = __builtin_amdgcn_mfma_f32_16x16x32_f16(afh[kc][0], b1v, bacc[nj], 0, 0, 0);
        bacc[nj] = __builtin_amdgcn_mfma_f32_16x16x32_f16(afh[kc][1], b0v, bacc[nj], 0, 0, 0);
      }
    }
    const int rowb = (lane >> 4) * 4;
#pragma unroll
    for (int nj = 0; nj < 2; ++nj) {
      const int col = (wn * 2 + nj) * 16 + lr;
      const float bv = bpre128[col];
#pragma unroll
      for (int q = 0; q < 4; ++q) {
        bsh[rowb + q][col] = bacc[nj][q] + bv;
      }
    }
  }
  __syncthreads();

  // ---- step B: aggregation, 4 nodes per wave, split-f16 DMA gathers ----
  for (int i = 0; i < 4; ++i) {
    const int lrow = wid * 4 + i;
    const int n = r0 + lrow;
    int sv[KK];
    float wv[KK];
    {
      const int4* sp4 = (const int4*)(src + (size_t)n * KK);
      const float4* ep4 = (const float4*)(eig + (size_t)n * KK * 2);
#pragma unroll
      for (int t = 0; t < 4; ++t) {
        const int4 s4 = sp4[t];
        sv[4 * t + 0] = s4.x;
        sv[4 * t + 1] = s4.y;
        sv[4 * t + 2] = s4.z;
        sv[4 * t + 3] = s4.w;
      }
#pragma unroll
      for (int t = 0; t < 8; ++t) {
        const float4 e4 = ep4[t];
        wv[2 * t + 0] = e4.y;
        wv[2 * t + 1] = e4.w;
      }
    }
    // drain DS queue before re-targeting stage (race guard); issue chunk 0
    asm volatile("s_waitcnt lgkmcnt(0)" ::: "memory");
    __builtin_amdgcn_global_load_lds(GCAST(preAh + (size_t)sv[0 + grow4] * 128 + gcol8),
                                     SCAST(&stageH[wid][0][0]), 16, 0, 0);
    __builtin_amdgcn_global_load_lds(GCAST(preAh + (size_t)sv[4 + grow4] * 128 + gcol8),
                                     SCAST(&stageH[wid][4][0]), 16, 0, 0);
    __builtin_amdgcn_global_load_lds(GCAST(preAl + (size_t)sv[0 + grow4] * 128 + gcol8),
                                     SCAST(&stageL[wid][0][0]), 16, 0, 0);
    __builtin_amdgcn_global_load_lds(GCAST(preAl + (size_t)sv[4 + grow4] * 128 + gcol8),
                                     SCAST(&stageL[wid][4][0]), 16, 0, 0);
    // weights (VALU overlaps DMA)
    float denom = 0.f;
#pragma unroll
    for (int e = 0; e < KK; ++e) denom += fabsf(wv[e]);
    denom += 1e-8f;
    const float inv = 1.f / denom;
    float sum_ew = 0.f;
#pragma unroll
    for (int e = 0; e < KK; ++e) {
      wv[e] *= inv;
      sum_ew += wv[e];
    }
    float sA0 = 0.f, sA1 = 0.f, wA0 = 0.f, wA1 = 0.f;
    float mA0 = -3.402823466e+38f, mA1 = -3.402823466e+38f;
    asm volatile("s_waitcnt vmcnt(0)" ::: "memory");
#pragma unroll
    for (int e = 0; e < 8; ++e) {
      const h2 ah2 = *(const h2*)&stageH[wid][e][d0];
      const h2 al2 = *(const h2*)&stageL[wid][e][d0];
      const float ax = (float)ah2[0] + (float)al2[0];
      const float ay = (float)ah2[1] + (float)al2[1];
      sA0 += ax;
      sA1 += ay;
      wA0 = fmaf(wv[e], ax, wA0);
      wA1 = fmaf(wv[e], ay, wA1);
      mA0 = fmaxf(mA0, ax);
      mA1 = fmaxf(mA1, ay);
    }
    // drain DS queue, issue chunk 1 (rows 8..15)
    asm volatile("s_waitcnt lgkmcnt(0)" ::: "memory");
    __builtin_amdgcn_global_load_lds(GCAST(preAh + (size_t)sv[8 + grow4] * 128 + gcol8),
                                     SCAST(&stageH[wid][0][0]), 16, 0, 0);
    __builtin_amdgcn_global_load_lds(GCAST(preAh + (size_t)sv[12 + grow4] * 128 + gcol8),
                                     SCAST(&stageH[wid][4][0]), 16, 0, 0);
    __builtin_amdgcn_global_load_lds(GCAST(preAl + (size_t)sv[8 + grow4] * 128 + gcol8),
                                     SCAST(&stageL[wid][0][0]), 16, 0, 0);
    __builtin_amdgcn_global_load_lds(GCAST(preAl + (size_t)sv[12 + grow4] * 128 + gcol8),
                                     SCAST(&stageL[wid][4][0]), 16, 0, 0);
    asm volatile("s_waitcnt vmcnt(0)" ::: "memory");
#pragma unroll
    for (int e = 0; e < 8; ++e) {
      const h2 ah2 = *(const h2*)&stageH[wid][e][d0];
      const h2 al2 = *(const h2*)&stageL[wid][e][d0];
      const float ax = (float)ah2[0] + (float)al2[0];
      const float ay = (float)ah2[1] + (float)al2[1];
      const float w = wv[8 + e];
      sA0 += ax;
      sA1 += ay;
      wA0 = fmaf(w, ax, wA0);
      wA1 = fmaf(w, ay, wA1);
      mA0 = fmaxf(mA0, ax);
      mA1 = fmaxf(mA1, ay);
    }
    const float2 b = {bsh[lrow][d0], bsh[lrow][d0 + 1]};
    const h2 hh2 = *(const h2*)(Hh + (size_t)n * 128 + d0);
    const h2 hl2 = *(const h2*)(Hl + (size_t)n * 128 + d0);
    const float hx = (float)hh2[0] + (float)hl2[0];
    const float hy = (float)hh2[1] + (float)hl2[1];
    auto wr2 = [&](int kcol, float v0, float v1) {
      h2 hi, lo;
      hi[0] = (half_t)v0;
      hi[1] = (half_t)v1;
      lo[0] = (half_t)(v0 - (float)hi[0]);
      lo[1] = (half_t)(v1 - (float)hi[1]);
      *(h2*)&Ah[lrow][kcol] = hi;
      *(h2*)&Al[lrow][kcol] = lo;
    };
    wr2(d0, sA0 + 16.f * b.x, sA1 + 16.f * b.y);
    wr2(128 + d0, mA0 + b.x, mA1 + b.y);
    wr2(256 + d0, fabsf(wA0 + sum_ew * (b.x - hx)), fabsf(wA1 + sum_ew * (b.y - hy)));
  }
  __syncthreads();

  // ---- step C: GEMM over K=512, wave tile 16 x 32 ----
  f32x4 acc[2] = {};
#pragma unroll
  for (int kc = 0; kc < 16; ++kc) {
    h8 a0, a1;
    if (kc < 4) {
      a0 = afh[kc & 3][0];
      a1 = afh[kc & 3][1];
    } else {
      a0 = *(const h8*)&Ah[lr][(kc - 4) * 32 + lk];
      a1 = *(const h8*)&Al[lr][(kc - 4) * 32 + lk];
    }
#pragma unroll
    for (int nj = 0; nj < 2; ++nj) {
      const size_t fi = ((size_t)((wn * 2 + nj) * 16 + kc) * 64 + lane) * 8;
      const h8 b0v = *(const h8*)(Wh + fi);
      const h8 b1v = *(const h8*)(Wl + fi);
      acc[nj] = __builtin_amdgcn_mfma_f32_16x16x32_f16(a0, b0v, acc[nj], 0, 0, 0);
      acc[nj] = __builtin_amdgcn_mfma_f32_16x16x32_f16(a0, b1v, acc[nj], 0, 0, 0);
      acc[nj] = __builtin_amdgcn_mfma_f32_16x16x32_f16(a1, b0v, acc[nj], 0, 0, 0);
    }
  }

  // ---- epilogue: hn = h_old + relu((acc+bias)*snorm); write split-f16 -----
  const int rowb = r0 + (lane >> 4) * 4;
#pragma unroll
  for (int nj = 0; nj < 2; ++nj) {
    const int col = wn * 32 + nj * 16 + lr;
    const float bv = bias[col];
#pragma unroll
    for (int q = 0; q < 4; ++q) {
      const int r = rowb + q;
      float a = acc[nj][q] + bv;
      a *= snorm[r];
      a = fmaxf(a, 0.f);
      const size_t off = (size_t)r * 128 + col;
      const float hold = (float)Hh[off] + (float)Hl[off];
      const float hn = hold + a;
      const half_t hi = (half_t)hn;
      Hh[off] = hi;
      Hl[off] = (half_t)(hn - (float)hi);
    }
  }
}

// ---------------- fused graph-mean + readout MLP (64 blocks) ---------------
__global__ __launch_bounds__(256) void reduce_mlp_k(const half_t* __restrict__ Hh,
                                                    const half_t* __restrict__ Hl,
                                                    const float* __restrict__ W0, const float* __restrict__ b0,
                                                    const float* __restrict__ W1, const float* __restrict__ b1,
                                                    const float* __restrict__ W2, const float* __restrict__ b2,
                                                    float* __restrict__ out) {
  __shared__ float hgs[128];
  __shared__ float red[128];
  __shared__ float y0s[64];
  __shared__ float y1s[32];
  __shared__ float wb[64 * 130];
  const int g = blockIdx.x;
  const int t = threadIdx.x;
  {
    const int d = t & 127, hf = t >> 7;
    const size_t base = ((size_t)g * NPG + (size_t)hf * 200) * 128 + d;
    float acc = 0.f;
    for (int i = 0; i < 200; ++i) {
      const size_t off = base + (size_t)i * 128;
      acc += (float)Hh[off] + (float)Hl[off];
    }
    if (hf) red[d] = acc;
    __syncthreads();
    if (!hf) hgs[d] = (acc + red[d]) * (1.f / (float)NPG);
  }
  __syncthreads();
  for (int idx = t; idx < 64 * 128; idx += 256) {
    wb[(idx >> 7) * 130 + (idx & 127)] = W0[idx];
  }
  __syncthreads();
  if (t < 64) {
    float a = b0[t];
    const float* w = &wb[t * 130];
    for (int k = 0; k < 128; ++k) a = fmaf(hgs[k], w[k], a);
    y0s[t] = fmaxf(a, 0.f);
  }
  __syncthreads();
  for (int idx = t; idx < 32 * 64; idx += 256) {
    wb[(idx >> 6) * 66 + (idx & 63)] = W1[idx];
  }
  __syncthreads();
  if (t < 32) {
    float a = b1[t];
    const float* w = &wb[t * 66];
    for (int k = 0; k < 64; ++k) a = fmaf(y0s[k], w[k], a);
    y1s[t] = fmaxf(a, 0.f);
  }
  __syncthreads();
  for (int idx = t; idx < 128 * 32; idx += 256) {
    wb[(idx >> 5) * 34 + (idx & 31)] = W2[idx];
  }
  __syncthreads();
  if (t < 128) {
    float a = b2[t];
    const float* w = &wb[t * 34];
    for (int k = 0; k < 32; ++k) a = fmaf(y1s[k], w[k], a);
    out[(size_t)g * 128 + t] = a;
  }
}

extern "C" void kernel_launch(void* const* d_in, const int* in_sizes, int n_in,
                              void* d_out, int out_size, void* d_ws, size_t ws_size,
                              hipStream_t stream) {
  const int* node_feat = (const int*)d_in[0];
  const int* src = (const int*)d_in[1];
  // d_in[2] = dst (repeat(arange(N),16)), unused
  const float* eig = (const float*)d_in[3];
  const float* snorm = (const float*)d_in[4];
  // d_in[5] = graph_ids, unused
  const float* emb = (const float*)d_in[6];
  const float* preW = (const float*)d_in[7];
  const float* preb = (const float*)d_in[8];
  const float* postW = (const float*)d_in[9];
  const float* postb = (const float*)d_in[10];
  const float* rW0 = (const float*)d_in[11];
  const float* rb0 = (const float*)d_in[12];
  const float* rW1 = (const float*)d_in[13];
  const float* rb1 = (const float*)d_in[14];
  const float* rW2 = (const float*)d_in[15];
  const float* rb2 = (const float*)d_in[16];
  float* out = (float*)d_out;

  half_t* Hh = (half_t*)d_ws;                        // N*128
  half_t* Hl = Hh + (size_t)NN * 128;                // N*128
  half_t* preAh = Hl + (size_t)NN * 128;             // N*128 split-f16
  half_t* preAl = preAh + (size_t)NN * 128;          // N*128
  half_t* WpreH = preAl + (size_t)NN * 128;          // L*32768 frag-major
  half_t* WpreL = WpreH + (size_t)LL * 32768;
  half_t* WpostH = WpreL + (size_t)LL * 32768;       // L*65536 frag-major
  half_t* WpostL = WpostH + (size_t)LL * 65536;
  float* bpre = (float*)(WpostL + (size_t)LL * 65536); // L*256

  prep_k<<<1540, 256, 0, stream>>>(preW, preb, postW, WpreH, WpreL, bpre, WpostH, WpostL);
  embed_k<<<(NN * 32) / 256, 256, 0, stream>>>(node_feat, emb, Hh, Hl);

  for (int l = 0; l < LL; ++l) {
    pre_gemm_k<<<NN / 64, 256, 0, stream>>>(
        Hh, Hl, WpreH + (size_t)l * 32768, WpreL + (size_t)l * 32768, preAh, preAl);
    agg_post_k<<<NN / 16, 256, 0, stream>>>(
        preAh, preAl, src, eig,
        WpreH + (size_t)l * 32768, WpreL + (size_t)l * 32768,
        bpre + (size_t)l * 256 + 128,
        Hh, Hl,
        WpostH + (size_t)l * 65536, WpostL + (size_t)l * 65536,
        postb + (size_t)l * 128, snorm);
  }

  reduce_mlp_k<<<BB, 256, 0, stream>>>(Hh, Hl, rW0, rb0, rW1, rb1, rW2, rb2, out);
}